// Round 1
// baseline (366.672 us; speedup 1.0000x reference)
//
#include <hip/hip_runtime.h>
#include <cstdint>
#include <cstddef>

#define N_ENT 40000
#define DDIM  128
#define BSZ   1024

typedef short s16x8 __attribute__((ext_vector_type(8)));
typedef float f32x4 __attribute__((ext_vector_type(4)));

// ws layout (bytes), all 256-aligned:
//   0        : double acc (8)           [zeroed via hipMemsetAsync]
//   256      : enorm  f32[40000]        (160000)
//   160256   : cnorm  f32[2048]         (8192)
//   168448   : c_bf   u16[2048*128]     (524288)
//   692736   : c_f32  f32[2048*128]     (1048576)   [only for L1 fallback]
//   1741312  : ent_bf u16[40000*128]    (10240000)  -> total 11981312 B
#define OFF_ACC   0
#define OFF_ENORM 256
#define OFF_CNORM 160256
#define OFF_CBF   168448
#define OFF_CF32  692736
#define OFF_EBF   1741312

__device__ __forceinline__ unsigned short f2bf(float f) {
  uint32_t u = __float_as_uint(f);
  u += 0x7fffu + ((u >> 16) & 1u);   // round-to-nearest-even
  return (unsigned short)(u >> 16);
}

// One wave per entity row: convert to bf16 + exact fp32 squared norm.
__global__ __launch_bounds__(256) void prep_ent_k(const float* __restrict__ ent,
                                                  unsigned short* __restrict__ ent_bf,
                                                  float* __restrict__ enorm) {
  int row  = blockIdx.x * 4 + (threadIdx.x >> 6);
  int lane = threadIdx.x & 63;
  float2 v = reinterpret_cast<const float2*>(ent + (size_t)row * DDIM)[lane];
  ushort2 h; h.x = f2bf(v.x); h.y = f2bf(v.y);
  reinterpret_cast<ushort2*>(ent_bf + (size_t)row * DDIM)[lane] = h;
  float sq = fmaf(v.x, v.x, v.y * v.y);
  #pragma unroll
  for (int m = 32; m; m >>= 1) sq += __shfl_xor(sq, m);
  if (lane == 0) enorm[row] = sq;
}

// One wave per c-row (2048 rows: branch0 = pos, branch1 = neg).
__global__ __launch_bounds__(256) void prep_c_k(const float* __restrict__ ent,
                                                const int* __restrict__ pos_h,
                                                const int* __restrict__ neg_h,
                                                const float* __restrict__ rpos,
                                                const float* __restrict__ rneg,
                                                unsigned short* __restrict__ c_bf,
                                                float* __restrict__ c_f32,
                                                float* __restrict__ cnorm) {
  int row  = blockIdx.x * 4 + (threadIdx.x >> 6);   // 0..2047
  int lane = threadIdx.x & 63;
  int br = row >> 10, i = row & 1023;
  int h = br ? neg_h[i] : pos_h[i];
  const float* rs = br ? rneg : rpos;
  float2 e  = reinterpret_cast<const float2*>(ent + (size_t)h * DDIM)[lane];
  float2 rv = reinterpret_cast<const float2*>(rs + (size_t)i * DDIM)[lane];
  float cx = e.x + rv.x, cy = e.y + rv.y;
  float2 cf; cf.x = cx; cf.y = cy;
  reinterpret_cast<float2*>(c_f32 + (size_t)row * DDIM)[lane] = cf;
  ushort2 hh; hh.x = f2bf(cx); hh.y = f2bf(cy);
  reinterpret_cast<ushort2*>(c_bf + (size_t)row * DDIM)[lane] = hh;
  float sq = fmaf(cx, cx, cy * cy);
  #pragma unroll
  for (int m = 32; m; m >>= 1) sq += __shfl_xor(sq, m);
  if (lane == 0) cnorm[row] = sq;
}

// Main: 128x128 tile per block, 2x2 waves, 4x4 16x16x32 MFMA tiles per wave.
// Fragments loaded directly from global (row-major [row][k] matches
// X[lane&15][quad*8+j] fragment layout for both A and B^T operands).
__global__ __launch_bounds__(256) void main_k(const unsigned short* __restrict__ c_bf,
                                              const unsigned short* __restrict__ ent_bf,
                                              const float* __restrict__ cnorm,
                                              const float* __restrict__ enorm,
                                              const int* __restrict__ pos_t,
                                              const int* __restrict__ l1_flag,
                                              const float* __restrict__ c_f32,
                                              const float* __restrict__ ent_f32,
                                              double* __restrict__ acc_d) {
  const int branch = blockIdx.x & 1;
  const int it = blockIdx.x >> 1;          // 0..7
  const int jt = blockIdx.y;               // 0..312
  const int i0 = it * 128, j0 = jt * 128;
  const int tid = threadIdx.x, lane = tid & 63, wv = tid >> 6;
  const int wm = wv >> 1, wn = wv & 1;
  const int r15 = lane & 15, quad = lane >> 4;

  const unsigned short* Abase = c_bf + ((size_t)(branch << 10) + i0) * DDIM;

  f32x4 acc[4][4];
  const f32x4 zf = {0.f, 0.f, 0.f, 0.f};
  #pragma unroll
  for (int a = 0; a < 4; ++a)
    #pragma unroll
    for (int b = 0; b < 4; ++b) acc[a][b] = zf;

  const s16x8* ap[4];
  const s16x8* bp[4];
  #pragma unroll
  for (int tm = 0; tm < 4; ++tm)
    ap[tm] = reinterpret_cast<const s16x8*>(Abase + (size_t)(wm * 64 + tm * 16 + r15) * DDIM + quad * 8);
  #pragma unroll
  for (int tn = 0; tn < 4; ++tn) {
    int jg = j0 + wn * 64 + tn * 16 + r15;
    int jc = jg < N_ENT ? jg : N_ENT - 1;      // clamp OOB rows; masked in epilogue
    bp[tn] = reinterpret_cast<const s16x8*>(ent_bf + (size_t)jc * DDIM + quad * 8);
  }

  #pragma unroll
  for (int kc = 0; kc < 4; ++kc) {
    s16x8 av[4], bv[4];
    #pragma unroll
    for (int tm = 0; tm < 4; ++tm) av[tm] = ap[tm][kc * 4];
    #pragma unroll
    for (int tn = 0; tn < 4; ++tn) bv[tn] = bp[tn][kc * 4];
    #pragma unroll
    for (int tm = 0; tm < 4; ++tm)
      #pragma unroll
      for (int tn = 0; tn < 4; ++tn)
        acc[tm][tn] = __builtin_amdgcn_mfma_f32_16x16x32_bf16(av[tm], bv[tn], acc[tm][tn], 0, 0, 0);
  }

  // Epilogue: sq = cn + en - 2*dot ; s = 100/dist ; bce terms with f32-clip clamps.
  const int l1 = *l1_flag;
  const float LS_MIN = -15.9423847f;        // ln(2^-23) = ln(1 - fl32(1-1e-7))
  const float LP_MAX = -1.1920929e-7f;      // ln(fl32(1-1e-7))
  float lsum = 0.f;

  #pragma unroll
  for (int tm = 0; tm < 4; ++tm) {
    #pragma unroll
    for (int r = 0; r < 4; ++r) {
      int ig = i0 + wm * 64 + tm * 16 + quad * 4 + r;     // 0..1023
      float cn = cnorm[(branch << 10) + ig];
      int tgt = branch ? -1 : pos_t[ig];
      #pragma unroll
      for (int tn = 0; tn < 4; ++tn) {
        int jg = j0 + wn * 64 + tn * 16 + r15;
        if (jg < N_ENT) {
          float s;
          if (!l1) {
            float dot = acc[tm][tn][r];
            float sq = fmaxf(fmaf(-2.f, dot, cn + enorm[jg]), 0.f);
            s = 100.f * rsqrtf(sq);                       // sq=0 -> inf, clamped below
          } else {
            // L1 fallback (never taken with this harness's inputs)
            const float* cp = c_f32 + ((size_t)(branch << 10) + ig) * DDIM;
            const float* ep = ent_f32 + (size_t)jg * DDIM;
            float man = 0.f;
            #pragma unroll 1
            for (int d = 0; d < DDIM; ++d) man += fabsf(cp[d] - ep[d]);
            s = 100.f / fmaxf(man, 1e-12f);
          }
          float e  = __expf(-s);                 // s>0 -> e in [0,1)
          float L  = __logf(1.f + e);            // log1p(e^-s)
          float ls = fmaxf(-(s + L), LS_MIN);    // log(1-pred) with clip emulation
          lsum += ls;
          if (jg == tgt) lsum += fminf(-L, LP_MAX) - ls;   // swap in log(pred) at target
        }
      }
    }
  }

  #pragma unroll
  for (int m = 32; m; m >>= 1) lsum += __shfl_xor(lsum, m);
  if (lane == 0) atomicAdd(acc_d, (double)lsum);
}

__global__ void finalize_k(const double* __restrict__ acc, float* __restrict__ out) {
  out[0] = (float)(-acc[0] / (double)((long long)BSZ * N_ENT));
}

extern "C" void kernel_launch(void* const* d_in, const int* in_sizes, int n_in,
                              void* d_out, int out_size, void* d_ws, size_t ws_size,
                              hipStream_t stream) {
  const int*   pos_h = (const int*)d_in[0];
  const int*   pos_t = (const int*)d_in[1];
  const int*   neg_h = (const int*)d_in[2];
  // d_in[3] = neg_t_batch (unused by reference)
  const float* rpos  = (const float*)d_in[4];
  const float* rneg  = (const float*)d_in[5];
  const float* ent   = (const float*)d_in[6];
  const int*   l1    = (const int*)d_in[7];

  char* ws = (char*)d_ws;
  double*         acc    = (double*)(ws + OFF_ACC);
  float*          enorm  = (float*)(ws + OFF_ENORM);
  float*          cnorm  = (float*)(ws + OFF_CNORM);
  unsigned short* c_bf   = (unsigned short*)(ws + OFF_CBF);
  float*          c_f32  = (float*)(ws + OFF_CF32);
  unsigned short* ent_bf = (unsigned short*)(ws + OFF_EBF);

  hipMemsetAsync(acc, 0, sizeof(double), stream);

  prep_ent_k<<<N_ENT / 4, 256, 0, stream>>>(ent, ent_bf, enorm);
  prep_c_k<<<2048 / 4, 256, 0, stream>>>(ent, pos_h, neg_h, rpos, rneg, c_bf, c_f32, cnorm);

  dim3 grid(16, (N_ENT + 127) / 128);   // x = (i-tile, branch) fastest for L2 sharing of j-tiles
  main_k<<<grid, 256, 0, stream>>>(c_bf, ent_bf, cnorm, enorm, pos_t, l1, c_f32, ent, acc);

  finalize_k<<<1, 1, 0, stream>>>(acc, (float*)d_out);
}

// Round 2
// 196.033 us; speedup vs baseline: 1.8705x; 1.8705x over previous
//
#include <hip/hip_runtime.h>
#include <cstdint>
#include <cstddef>

#define N_ENT 40000
#define DDIM  128
#define BSZ   1024
#define NJT   313               // ceil(40000/128)
#define NPART (16 * NJT)        // grid blocks = 5008

typedef short s16x8 __attribute__((ext_vector_type(8)));
typedef float f32x4 __attribute__((ext_vector_type(4)));

// ws layout (bytes):
//   0       : partials f32[5008]  (20032, rounded to 20224)
//   20224   : enorm  f32[40000]   (160000)
//   180224  : cnorm  f32[2048]    (8192)
//   188416  : c_bf   u16[2048*128](524288)
//   712704  : ent_bf u16[40000*128](10240000) -> total 10952704 B
#define OFF_PART  0
#define OFF_ENORM 20224
#define OFF_CNORM 180224
#define OFF_CBF   188416
#define OFF_EBF   712704

__device__ __forceinline__ unsigned short f2bf(float f) {
  uint32_t u = __float_as_uint(f);
  u += 0x7fffu + ((u >> 16) & 1u);   // round-to-nearest-even
  return (unsigned short)(u >> 16);
}

// One wave per entity row: convert to bf16 + exact fp32 squared norm.
__global__ __launch_bounds__(256) void prep_ent_k(const float* __restrict__ ent,
                                                  unsigned short* __restrict__ ent_bf,
                                                  float* __restrict__ enorm) {
  int row  = blockIdx.x * 4 + (threadIdx.x >> 6);
  int lane = threadIdx.x & 63;
  float2 v = reinterpret_cast<const float2*>(ent + (size_t)row * DDIM)[lane];
  ushort2 h; h.x = f2bf(v.x); h.y = f2bf(v.y);
  reinterpret_cast<ushort2*>(ent_bf + (size_t)row * DDIM)[lane] = h;
  float sq = fmaf(v.x, v.x, v.y * v.y);
  #pragma unroll
  for (int m = 32; m; m >>= 1) sq += __shfl_xor(sq, m);
  if (lane == 0) enorm[row] = sq;
}

// One wave per c-row (2048 rows: branch0 = pos, branch1 = neg).
__global__ __launch_bounds__(256) void prep_c_k(const float* __restrict__ ent,
                                                const int* __restrict__ pos_h,
                                                const int* __restrict__ neg_h,
                                                const float* __restrict__ rpos,
                                                const float* __restrict__ rneg,
                                                unsigned short* __restrict__ c_bf,
                                                float* __restrict__ cnorm) {
  int row  = blockIdx.x * 4 + (threadIdx.x >> 6);   // 0..2047
  int lane = threadIdx.x & 63;
  int br = row >> 10, i = row & 1023;
  int h = br ? neg_h[i] : pos_h[i];
  const float* rs = br ? rneg : rpos;
  float2 e  = reinterpret_cast<const float2*>(ent + (size_t)h * DDIM)[lane];
  float2 rv = reinterpret_cast<const float2*>(rs + (size_t)i * DDIM)[lane];
  float cx = e.x + rv.x, cy = e.y + rv.y;
  ushort2 hh; hh.x = f2bf(cx); hh.y = f2bf(cy);
  reinterpret_cast<ushort2*>(c_bf + (size_t)row * DDIM)[lane] = hh;
  float sq = fmaf(cx, cx, cy * cy);
  #pragma unroll
  for (int m = 32; m; m >>= 1) sq += __shfl_xor(sq, m);
  if (lane == 0) cnorm[row] = sq;
}

// Main: 128x128 tile per block, 2x2 waves, 4x4 16x16x32 MFMA tiles per wave.
// Fragments loaded directly from global (row-major [row][k] matches
// X[lane&15][quad*8+j] fragment layout for both A and B^T operands).
// NO atomics: one float partial per block.
__global__ __launch_bounds__(256) void main_k(const unsigned short* __restrict__ c_bf,
                                              const unsigned short* __restrict__ ent_bf,
                                              const float* __restrict__ cnorm,
                                              const float* __restrict__ enorm,
                                              const int* __restrict__ pos_t,
                                              const int* __restrict__ l1_flag,
                                              const int* __restrict__ pos_h,
                                              const int* __restrict__ neg_h,
                                              const float* __restrict__ rpos,
                                              const float* __restrict__ rneg,
                                              const float* __restrict__ ent_f32,
                                              float* __restrict__ partials) {
  const int branch = blockIdx.x & 1;
  const int it = blockIdx.x >> 1;          // 0..7
  const int jt = blockIdx.y;               // 0..312
  const int i0 = it * 128, j0 = jt * 128;
  const int tid = threadIdx.x, lane = tid & 63, wv = tid >> 6;
  const int wm = wv >> 1, wn = wv & 1;
  const int r15 = lane & 15, quad = lane >> 4;

  const unsigned short* Abase = c_bf + ((size_t)(branch << 10) + i0) * DDIM;

  f32x4 acc[4][4];
  const f32x4 zf = {0.f, 0.f, 0.f, 0.f};
  #pragma unroll
  for (int a = 0; a < 4; ++a)
    #pragma unroll
    for (int b = 0; b < 4; ++b) acc[a][b] = zf;

  const s16x8* ap[4];
  const s16x8* bp[4];
  #pragma unroll
  for (int tm = 0; tm < 4; ++tm)
    ap[tm] = reinterpret_cast<const s16x8*>(Abase + (size_t)(wm * 64 + tm * 16 + r15) * DDIM + quad * 8);
  #pragma unroll
  for (int tn = 0; tn < 4; ++tn) {
    int jg = j0 + wn * 64 + tn * 16 + r15;
    int jc = jg < N_ENT ? jg : N_ENT - 1;      // clamp OOB rows; masked in epilogue
    bp[tn] = reinterpret_cast<const s16x8*>(ent_bf + (size_t)jc * DDIM + quad * 8);
  }

  #pragma unroll
  for (int kc = 0; kc < 4; ++kc) {
    s16x8 av[4], bv[4];
    #pragma unroll
    for (int tm = 0; tm < 4; ++tm) av[tm] = ap[tm][kc * 4];
    #pragma unroll
    for (int tn = 0; tn < 4; ++tn) bv[tn] = bp[tn][kc * 4];
    #pragma unroll
    for (int tm = 0; tm < 4; ++tm)
      #pragma unroll
      for (int tn = 0; tn < 4; ++tn)
        acc[tm][tn] = __builtin_amdgcn_mfma_f32_16x16x32_bf16(av[tm], bv[tn], acc[tm][tn], 0, 0, 0);
  }

  // Epilogue. sq = cn + en - 2*dot ; s = 100/dist ; bce with f32-clip clamps.
  // log1p(e^-s) ~= x - x^2/2 (x=e^-s<=0.05 for s>=3; abs err <= 4e-5).
  const int l1 = *l1_flag;
  const float LS_MIN = -15.9423847f;        // ln(2^-23) = ln(1 - fl32(1-1e-7))
  const float LP_MAX = -1.1920929e-7f;      // ln(fl32(1-1e-7))
  float lsum = 0.f;

  // enorm depends only on tn: 4 loads per thread.
  float en[4];
  #pragma unroll
  for (int tn = 0; tn < 4; ++tn) {
    int jg = j0 + wn * 64 + tn * 16 + r15;
    en[tn] = enorm[jg < N_ENT ? jg : N_ENT - 1];
  }

  const bool full = (j0 + 128) <= N_ENT;     // block-uniform

  if (!l1) {
    #pragma unroll
    for (int tm = 0; tm < 4; ++tm) {
      #pragma unroll
      for (int r = 0; r < 4; ++r) {
        int ig = i0 + wm * 64 + tm * 16 + quad * 4 + r;     // 0..1023
        float cn = cnorm[(branch << 10) + ig];
        int tgt = branch ? -1 : pos_t[ig];
        if (full) {
          #pragma unroll
          for (int tn = 0; tn < 4; ++tn) {
            int jg = j0 + wn * 64 + tn * 16 + r15;
            float sq = fmaxf(fmaf(-2.f, acc[tm][tn][r], cn + en[tn]), 0.f);
            float s  = 100.f * rsqrtf(sq);            // sq=0 -> inf, clamped below
            float x  = __expf(-s);
            float L  = fmaf(-0.5f * x, x, x);         // log1p(x)
            float ls = fmaxf(-(s + L), LS_MIN);       // log(1-pred)
            lsum += ls;
            if (jg == tgt) lsum += fminf(-L, LP_MAX) - ls;
          }
        } else {
          #pragma unroll
          for (int tn = 0; tn < 4; ++tn) {
            int jg = j0 + wn * 64 + tn * 16 + r15;
            if (jg < N_ENT) {
              float sq = fmaxf(fmaf(-2.f, acc[tm][tn][r], cn + en[tn]), 0.f);
              float s  = 100.f * rsqrtf(sq);
              float x  = __expf(-s);
              float L  = fmaf(-0.5f * x, x, x);
              float ls = fmaxf(-(s + L), LS_MIN);
              lsum += ls;
              if (jg == tgt) lsum += fminf(-L, LP_MAX) - ls;
            }
          }
        }
      }
    }
  } else {
    // L1 fallback (never taken with this harness's inputs; recompute c on the fly)
    const float* rs = branch ? rneg : rpos;
    const int*   hb = branch ? neg_h : pos_h;
    #pragma unroll 1
    for (int tm = 0; tm < 4; ++tm) {
      #pragma unroll 1
      for (int r = 0; r < 4; ++r) {
        int ig = i0 + wm * 64 + tm * 16 + quad * 4 + r;
        int bi = ig;                                   // 0..1023 batch row
        int h  = hb[bi];
        int tgt = branch ? -1 : pos_t[bi];
        #pragma unroll 1
        for (int tn = 0; tn < 4; ++tn) {
          int jg = j0 + wn * 64 + tn * 16 + r15;
          if (jg < N_ENT) {
            const float* cp1 = ent_f32 + (size_t)h * DDIM;
            const float* cp2 = rs + (size_t)bi * DDIM;
            const float* ep  = ent_f32 + (size_t)jg * DDIM;
            float man = 0.f;
            #pragma unroll 1
            for (int d = 0; d < DDIM; ++d) man += fabsf(cp1[d] + cp2[d] - ep[d]);
            float s  = 100.f / fmaxf(man, 1e-12f);
            float e  = __expf(-s);
            float L  = __logf(1.f + e);
            float ls = fmaxf(-(s + L), LS_MIN);
            lsum += ls;
            if (jg == tgt) lsum += fminf(-L, LP_MAX) - ls;
          }
        }
      }
    }
  }

  // Block reduction -> one partial per block (no atomics).
  #pragma unroll
  for (int m = 32; m; m >>= 1) lsum += __shfl_xor(lsum, m);
  __shared__ float s4[4];
  if (lane == 0) s4[wv] = lsum;
  __syncthreads();
  if (tid == 0)
    partials[blockIdx.y * 16 + blockIdx.x] = s4[0] + s4[1] + s4[2] + s4[3];
}

__global__ __launch_bounds__(256) void finalize_k(const float* __restrict__ partials,
                                                  float* __restrict__ out) {
  int tid = threadIdx.x, lane = tid & 63, wv = tid >> 6;
  double t = 0.0;
  for (int i = tid; i < NPART; i += 256) t += (double)partials[i];
  #pragma unroll
  for (int m = 32; m; m >>= 1) t += __shfl_xor(t, m);
  __shared__ double sd[4];
  if (lane == 0) sd[wv] = t;
  __syncthreads();
  if (tid == 0)
    out[0] = (float)(-(sd[0] + sd[1] + sd[2] + sd[3]) / ((double)BSZ * (double)N_ENT));
}

extern "C" void kernel_launch(void* const* d_in, const int* in_sizes, int n_in,
                              void* d_out, int out_size, void* d_ws, size_t ws_size,
                              hipStream_t stream) {
  const int*   pos_h = (const int*)d_in[0];
  const int*   pos_t = (const int*)d_in[1];
  const int*   neg_h = (const int*)d_in[2];
  // d_in[3] = neg_t_batch (unused by reference)
  const float* rpos  = (const float*)d_in[4];
  const float* rneg  = (const float*)d_in[5];
  const float* ent   = (const float*)d_in[6];
  const int*   l1    = (const int*)d_in[7];

  char* ws = (char*)d_ws;
  float*          partials = (float*)(ws + OFF_PART);
  float*          enorm    = (float*)(ws + OFF_ENORM);
  float*          cnorm    = (float*)(ws + OFF_CNORM);
  unsigned short* c_bf     = (unsigned short*)(ws + OFF_CBF);
  unsigned short* ent_bf   = (unsigned short*)(ws + OFF_EBF);

  prep_ent_k<<<N_ENT / 4, 256, 0, stream>>>(ent, ent_bf, enorm);
  prep_c_k<<<2048 / 4, 256, 0, stream>>>(ent, pos_h, neg_h, rpos, rneg, c_bf, cnorm);

  dim3 grid(16, NJT);   // x = (i-tile, branch) fastest for L2 sharing of j-tiles
  main_k<<<grid, 256, 0, stream>>>(c_bf, ent_bf, cnorm, enorm, pos_t, l1,
                                   pos_h, neg_h, rpos, rneg, ent, partials);

  finalize_k<<<1, 256, 0, stream>>>(partials, (float*)d_out);
}

// Round 3
// 174.100 us; speedup vs baseline: 2.1061x; 1.1260x over previous
//
#include <hip/hip_runtime.h>
#include <cstdint>
#include <cstddef>

#define N_ENT 40000
#define DDIM  128
#define BSZ   1024
#define NJT   313               // ceil(40000/128)
#define NPART (16 * NJT)        // main grid blocks = 5008

#define AS1 __attribute__((address_space(1)))
#define AS3 __attribute__((address_space(3)))

typedef short s16x8 __attribute__((ext_vector_type(8)));
typedef float f32x4 __attribute__((ext_vector_type(4)));

// ws layout (bytes), 256-aligned:
//   0       : partials f32[5008]   (main blocks)
//   20480   : tpart    f32[1024]   (target-pair fixups, written by prep)
//   24576   : enorm    f32[40000]
//   184576  : cnorm    f32[2048]
//   192768  : c_bf     u16[2048*128]
//   717056  : ent_bf   u16[40000*128]  -> total 10,957,056 B
#define OFF_PART  0
#define OFF_TPART 20480
#define OFF_ENORM 24576
#define OFF_CNORM 184576
#define OFF_CBF   192768
#define OFF_EBF   717056

#define LS_MIN (-15.9423847f)       // ln(2^-23) = ln(1 - fl32(1-1e-7))
#define LP_MAX (-1.1920929e-7f)     // ln(fl32(1-1e-7))

__device__ __forceinline__ unsigned short f2bf(float f) {
  uint32_t u = __float_as_uint(f);
  u += 0x7fffu + ((u >> 16) & 1u);   // round-to-nearest-even
  return (unsigned short)(u >> 16);
}

// Fused prep: blocks [0, 10000) convert entity rows (bf16 + fp32 norm);
// blocks [10000, 10512) build c rows; positive-branch rows also compute the
// exact fp32 target-pair fixup (B - A) so main_k needs NO per-element check.
__global__ __launch_bounds__(256) void prep_k(const float* __restrict__ ent,
                                              const int* __restrict__ pos_h,
                                              const int* __restrict__ pos_t,
                                              const int* __restrict__ neg_h,
                                              const float* __restrict__ rpos,
                                              const float* __restrict__ rneg,
                                              const int* __restrict__ l1_flag,
                                              unsigned short* __restrict__ ent_bf,
                                              float* __restrict__ enorm,
                                              unsigned short* __restrict__ c_bf,
                                              float* __restrict__ cnorm,
                                              float* __restrict__ tpart) {
  const int lane = threadIdx.x & 63, wv = threadIdx.x >> 6;
  const int blk = blockIdx.x;
  if (blk < N_ENT / 4) {
    int row = blk * 4 + wv;
    float2 v = reinterpret_cast<const float2*>(ent + (size_t)row * DDIM)[lane];
    ushort2 h; h.x = f2bf(v.x); h.y = f2bf(v.y);
    reinterpret_cast<ushort2*>(ent_bf + (size_t)row * DDIM)[lane] = h;
    float sq = fmaf(v.x, v.x, v.y * v.y);
    #pragma unroll
    for (int m = 32; m; m >>= 1) sq += __shfl_xor(sq, m);
    if (lane == 0) enorm[row] = sq;
  } else {
    int row = (blk - N_ENT / 4) * 4 + wv;       // 0..2047
    int br = row >> 10, i = row & 1023;
    int h = br ? neg_h[i] : pos_h[i];
    const float* rs = br ? rneg : rpos;
    float2 e  = reinterpret_cast<const float2*>(ent + (size_t)h * DDIM)[lane];
    float2 rv = reinterpret_cast<const float2*>(rs + (size_t)i * DDIM)[lane];
    float cx = e.x + rv.x, cy = e.y + rv.y;
    ushort2 hh; hh.x = f2bf(cx); hh.y = f2bf(cy);
    reinterpret_cast<ushort2*>(c_bf + (size_t)row * DDIM)[lane] = hh;
    float sq = fmaf(cx, cx, cy * cy);
    #pragma unroll
    for (int m = 32; m; m >>= 1) sq += __shfl_xor(sq, m);
    if (lane == 0) cnorm[row] = sq;
    if (br == 0) {
      // exact fp32 fixup for the single positive target in this row
      int t = pos_t[i];
      float2 et = reinterpret_cast<const float2*>(ent + (size_t)t * DDIM)[lane];
      float dx = cx - et.x, dy = cy - et.y;
      float d2 = fmaf(dx, dx, dy * dy);
      float m1 = fabsf(dx) + fabsf(dy);
      #pragma unroll
      for (int m = 32; m; m >>= 1) { d2 += __shfl_xor(d2, m); m1 += __shfl_xor(m1, m); }
      if (lane == 0) {
        float s = (*l1_flag) ? (100.f / fmaxf(m1, 1e-12f))
                             : (100.f * rsqrtf(fmaxf(d2, 0.f)));   // d2=0 -> inf, clamps below
        float x = __expf(-s);
        float L = log1pf(x);
        float B = fminf(-L, LP_MAX);             // log(pred)
        float A = fmaxf(-(s + L), LS_MIN);       // log(1-pred), what main_k adds
        tpart[i] = B - A;
      }
    }
  }
}

// Main: 128x128 tile/block, 2x2 waves, 4x4 16x16x32 MFMA tiles per wave.
// B (ent) tile staged to LDS via global_load_lds w=16 with XOR chunk swizzle
// (c' = c ^ (row&15)) -> ds_read_b128 fragments are 2-way (free).
// A fragments direct from L2-hot c_bf, double-buffered across kc.
// No target logic; no atomics; one float partial per block.
__global__ __launch_bounds__(256) void main_k(const unsigned short* __restrict__ c_bf,
                                              const unsigned short* __restrict__ ent_bf,
                                              const float* __restrict__ cnorm,
                                              const float* __restrict__ enorm,
                                              const int* __restrict__ l1_flag,
                                              const int* __restrict__ pos_h,
                                              const int* __restrict__ neg_h,
                                              const float* __restrict__ rpos,
                                              const float* __restrict__ rneg,
                                              const float* __restrict__ ent_f32,
                                              float* __restrict__ partials) {
  __shared__ unsigned short smem[128 * 128];    // 32 KB swizzled B tile
  const int branch = blockIdx.x & 1;
  const int it = blockIdx.x >> 1;               // 0..7
  const int jt = blockIdx.y;                    // 0..312
  const int i0 = it * 128, j0 = jt * 128;
  const int tid = threadIdx.x, lane = tid & 63, wv = tid >> 6;
  const int wm = wv >> 1, wn = wv & 1;
  const int r15 = lane & 15, quad = lane >> 4;

  // ---- async stage B tile: 2048 x 16B chunks, 8 per thread, swizzled ----
  #pragma unroll
  for (int i = 0; i < 8; ++i) {
    int g  = i * 256 + tid;        // LDS chunk id; per-wave contiguous 64-chunk runs
    int r  = g >> 4;               // tile row 0..127
    int cp = g & 15;               // swizzled chunk col
    int c  = cp ^ (r & 15);        // source chunk col
    int jr = j0 + r; if (jr >= N_ENT) jr = N_ENT - 1;   // clamp; excluded in epilogue
    const unsigned short* src = ent_bf + (size_t)jr * DDIM + c * 8;
    __builtin_amdgcn_global_load_lds((const AS1 void*)src, (AS3 void*)(&smem[g * 8]), 16, 0, 0);
  }

  // ---- A fragment pointers + prefetch kc=0 ----
  const unsigned short* Abase = c_bf + ((size_t)(branch << 10) + i0) * DDIM;
  const unsigned short* arow[4];
  #pragma unroll
  for (int tm = 0; tm < 4; ++tm)
    arow[tm] = Abase + (size_t)(wm * 64 + tm * 16 + r15) * DDIM + quad * 8;

  s16x8 av[2][4];
  #pragma unroll
  for (int tm = 0; tm < 4; ++tm)
    av[0][tm] = *reinterpret_cast<const s16x8*>(arow[tm]);

  f32x4 acc[4][4];
  const f32x4 zf = {0.f, 0.f, 0.f, 0.f};
  #pragma unroll
  for (int a = 0; a < 4; ++a)
    #pragma unroll
    for (int b = 0; b < 4; ++b) acc[a][b] = zf;

  __syncthreads();   // drains vmcnt: B tile staged (A kc0 also landed)

  #pragma unroll
  for (int kc = 0; kc < 4; ++kc) {
    if (kc < 3) {
      #pragma unroll
      for (int tm = 0; tm < 4; ++tm)
        av[(kc + 1) & 1][tm] = *reinterpret_cast<const s16x8*>(arow[tm] + (kc + 1) * 32);
    }
    s16x8 bv[4];
    #pragma unroll
    for (int tn = 0; tn < 4; ++tn) {
      int R  = wn * 64 + tn * 16 + r15;
      int cs = (kc * 4 + quad) ^ r15;
      bv[tn] = *reinterpret_cast<const s16x8*>(&smem[R * 128 + cs * 8]);
    }
    #pragma unroll
    for (int tm = 0; tm < 4; ++tm)
      #pragma unroll
      for (int tn = 0; tn < 4; ++tn)
        acc[tm][tn] = __builtin_amdgcn_mfma_f32_16x16x32_bf16(av[kc & 1][tm], bv[tn], acc[tm][tn], 0, 0, 0);
  }

  // ---- epilogue: sq = cn+en-2dot ; s = 100/dist ; add log(1-pred) ----
  const int l1 = *l1_flag;
  float lsum = 0.f;

  float en[4];
  #pragma unroll
  for (int tn = 0; tn < 4; ++tn) {
    int jg = j0 + wn * 64 + tn * 16 + r15;
    en[tn] = enorm[jg < N_ENT ? jg : N_ENT - 1];
  }
  float cnv[16];
  #pragma unroll
  for (int tm = 0; tm < 4; ++tm)
    #pragma unroll
    for (int r = 0; r < 4; ++r)
      cnv[tm * 4 + r] = cnorm[(branch << 10) + i0 + wm * 64 + tm * 16 + quad * 4 + r];

  const bool full = (j0 + 128) <= N_ENT;   // block-uniform

  if (!l1) {
    if (full) {
      #pragma unroll
      for (int tm = 0; tm < 4; ++tm) {
        #pragma unroll
        for (int tn = 0; tn < 4; ++tn) {
          float e0 = en[tn];
          #pragma unroll
          for (int r = 0; r < 4; ++r) {
            float sq = fmaxf(fmaf(-2.f, acc[tm][tn][r], cnv[tm * 4 + r] + e0), 0.f);
            float u  = rsqrtf(sq);                 // sq=0 -> inf, clamped below
            float s  = 100.f * u;
            float x  = __expf(-s);
            float L  = fmaf(-0.5f * x, x, x);      // log1p(x), x<=~0.05
            lsum += fmaxf(-(s + L), LS_MIN);       // log(1-pred)
          }
        }
      }
    } else {
      #pragma unroll
      for (int tm = 0; tm < 4; ++tm) {
        #pragma unroll
        for (int tn = 0; tn < 4; ++tn) {
          int jg = j0 + wn * 64 + tn * 16 + r15;
          if (jg < N_ENT) {
            float e0 = en[tn];
            #pragma unroll
            for (int r = 0; r < 4; ++r) {
              float sq = fmaxf(fmaf(-2.f, acc[tm][tn][r], cnv[tm * 4 + r] + e0), 0.f);
              float u  = rsqrtf(sq);
              float s  = 100.f * u;
              float x  = __expf(-s);
              float L  = fmaf(-0.5f * x, x, x);
              lsum += fmaxf(-(s + L), LS_MIN);
            }
          }
        }
      }
    }
  } else {
    // L1 fallback (dead with this harness's inputs): recompute c on the fly.
    const float* rs = branch ? rneg : rpos;
    const int*   hb = branch ? neg_h : pos_h;
    #pragma unroll 1
    for (int tm = 0; tm < 4; ++tm) {
      #pragma unroll 1
      for (int r = 0; r < 4; ++r) {
        int bi = i0 + wm * 64 + tm * 16 + quad * 4 + r;    // batch row 0..1023
        int h  = hb[bi];
        #pragma unroll 1
        for (int tn = 0; tn < 4; ++tn) {
          int jg = j0 + wn * 64 + tn * 16 + r15;
          if (jg < N_ENT) {
            const float* cp1 = ent_f32 + (size_t)h * DDIM;
            const float* cp2 = rs + (size_t)bi * DDIM;
            const float* ep  = ent_f32 + (size_t)jg * DDIM;
            float man = 0.f;
            #pragma unroll 1
            for (int d = 0; d < DDIM; ++d) man += fabsf(cp1[d] + cp2[d] - ep[d]);
            float s  = 100.f / fmaxf(man, 1e-12f);
            float e  = __expf(-s);
            float L  = __logf(1.f + e);
            lsum += fmaxf(-(s + L), LS_MIN);
          }
        }
      }
    }
  }

  // block reduction -> one partial per block
  #pragma unroll
  for (int m = 32; m; m >>= 1) lsum += __shfl_xor(lsum, m);
  __shared__ float s4[4];
  if (lane == 0) s4[wv] = lsum;
  __syncthreads();
  if (tid == 0)
    partials[blockIdx.y * 16 + blockIdx.x] = s4[0] + s4[1] + s4[2] + s4[3];
}

__global__ __launch_bounds__(256) void finalize_k(const float* __restrict__ partials,
                                                  const float* __restrict__ tpart,
                                                  float* __restrict__ out) {
  int tid = threadIdx.x, lane = tid & 63, wv = tid >> 6;
  double t = 0.0;
  for (int i = tid; i < NPART; i += 256) t += (double)partials[i];
  for (int i = tid; i < BSZ; i += 256) t += (double)tpart[i];
  #pragma unroll
  for (int m = 32; m; m >>= 1) t += __shfl_xor(t, m);
  __shared__ double sd[4];
  if (lane == 0) sd[wv] = t;
  __syncthreads();
  if (tid == 0)
    out[0] = (float)(-(sd[0] + sd[1] + sd[2] + sd[3]) / ((double)BSZ * (double)N_ENT));
}

extern "C" void kernel_launch(void* const* d_in, const int* in_sizes, int n_in,
                              void* d_out, int out_size, void* d_ws, size_t ws_size,
                              hipStream_t stream) {
  const int*   pos_h = (const int*)d_in[0];
  const int*   pos_t = (const int*)d_in[1];
  const int*   neg_h = (const int*)d_in[2];
  // d_in[3] = neg_t_batch (unused by reference)
  const float* rpos  = (const float*)d_in[4];
  const float* rneg  = (const float*)d_in[5];
  const float* ent   = (const float*)d_in[6];
  const int*   l1    = (const int*)d_in[7];

  char* ws = (char*)d_ws;
  float*          partials = (float*)(ws + OFF_PART);
  float*          tpart    = (float*)(ws + OFF_TPART);
  float*          enorm    = (float*)(ws + OFF_ENORM);
  float*          cnorm    = (float*)(ws + OFF_CNORM);
  unsigned short* c_bf     = (unsigned short*)(ws + OFF_CBF);
  unsigned short* ent_bf   = (unsigned short*)(ws + OFF_EBF);

  prep_k<<<N_ENT / 4 + 2048 / 4, 256, 0, stream>>>(ent, pos_h, pos_t, neg_h, rpos, rneg, l1,
                                                   ent_bf, enorm, c_bf, cnorm, tpart);

  dim3 grid(16, NJT);   // x = (i-tile, branch) fastest -> 16 blocks share each j-tile in L2
  main_k<<<grid, 256, 0, stream>>>(c_bf, ent_bf, cnorm, enorm, l1,
                                   pos_h, neg_h, rpos, rneg, ent, partials);

  finalize_k<<<1, 256, 0, stream>>>(partials, tpart, (float*)d_out);
}